// Round 1
// baseline (532.740 us; speedup 1.0000x reference)
//
#include <hip/hip_runtime.h>
#include <hip/hip_bf16.h>

typedef __attribute__((ext_vector_type(8))) short frag8;
typedef __attribute__((ext_vector_type(4))) float f32x4;

#define ASYNC16(gsrc, ldst) \
  __builtin_amdgcn_global_load_lds((const __attribute__((address_space(1))) void*)(gsrc), \
                                   (__attribute__((address_space(3))) void*)(ldst), 16, 0, 0)

__device__ __forceinline__ float sigmoid_(float x) { return 1.0f / (1.0f + __expf(-x)); }
__device__ __forceinline__ float tanh_(float x)    { return 1.0f - 2.0f / (__expf(2.0f * x) + 1.0f); }

// ---------------- prep: weight conversion / reorder ----------------
// Wg[n'][k], n' = u*4 + j (u=unit, j=gate i/f/g/o), k<512 -> W_ih, k>=512 -> W_hh
__global__ __launch_bounds__(256) void prep_kernel(
    const float* __restrict__ W_comb, const float* __restrict__ W_ih,
    const float* __restrict__ W_hh, const float* __restrict__ b_ih,
    const float* __restrict__ b_hh,
    __hip_bfloat16* __restrict__ Wc, __hip_bfloat16* __restrict__ Wg,
    float* __restrict__ biasg)
{
  int idx = blockIdx.x * 256 + threadIdx.x;
  const int NW = 2048 * 1024, NC = 512 * 512;
  if (idx < NW) {
    int np = idx >> 10, k = idx & 1023;
    int u = np >> 2, j = np & 3;
    int n = j * 512 + u;
    float v = (k < 512) ? W_ih[n * 512 + k] : W_hh[n * 512 + (k - 512)];
    Wg[idx] = __float2bfloat16(v);
  } else if (idx < NW + NC) {
    int t = idx - NW;
    int n = t >> 9, k = t & 511;
    Wc[t] = __float2bfloat16(W_comb[n * 513 + 1 + k]);   // skip col 0 (input)
  } else if (idx < NW + NC + 2048) {
    int np = idx - NW - NC;
    int u = np >> 2, j = np & 3;
    int n = j * 512 + u;
    biasg[np] = b_ih[n] + b_hh[n];
  }
}

// ---------------- attention: one wave per row ----------------
__global__ __launch_bounds__(256) void attn_kernel(
    const float* __restrict__ inputv, const float* __restrict__ hidden,
    const float* __restrict__ cell, const float* __restrict__ enc,
    const float* __restrict__ W_attn, const float* __restrict__ b_attn,
    __hip_bfloat16* __restrict__ A1, __hip_bfloat16* __restrict__ Z,
    float* __restrict__ outA)
{
  __shared__ float Wl[6 * 1025];
  const int tid = threadIdx.x;
  for (int i = tid; i < 6 * 1025; i += 256) Wl[i] = W_attn[i];
  __syncthreads();
  const int w = tid >> 6, lane = tid & 63;
  const long row = (long)blockIdx.x * 4 + w;

  const float* hp = hidden + row * 512;
  const float* cp = cell + row * 512;
  float h8[8];
  float acc[6] = {0.f, 0.f, 0.f, 0.f, 0.f, 0.f};
#pragma unroll
  for (int i = 0; i < 8; ++i) {
    int k = lane + i * 64;
    float hv = hp[k], cv = cp[k];
    h8[i] = hv;
#pragma unroll
    for (int s = 0; s < 6; ++s)
      acc[s] += hv * Wl[s * 1025 + 1 + k] + cv * Wl[s * 1025 + 513 + k];
  }
  float iv = inputv[row];
  float logit[6];
#pragma unroll
  for (int s = 0; s < 6; ++s) {
    float a = acc[s];
#pragma unroll
    for (int d = 32; d > 0; d >>= 1) a += __shfl_xor(a, d);
    logit[s] = a + iv * Wl[s * 1025] + b_attn[s];
  }
  float mx = logit[0];
#pragma unroll
  for (int s = 1; s < 6; ++s) mx = fmaxf(mx, logit[s]);
  float wts[6], tot = 0.f;
#pragma unroll
  for (int s = 0; s < 6; ++s) { wts[s] = __expf(logit[s] - mx); tot += wts[s]; }
  float rt = 1.f / tot;
#pragma unroll
  for (int s = 0; s < 6; ++s) wts[s] *= rt;
  if (lane < 6) {
    float mw = 0.f;
#pragma unroll
    for (int s = 0; s < 6; ++s) if (lane == s) mw = wts[s];
    outA[row * 6 + lane] = mw;
  }
  const float* ep = enc + row * 3072;
#pragma unroll
  for (int i = 0; i < 8; ++i) {
    int k = lane + i * 64;
    float a = 0.f;
#pragma unroll
    for (int s = 0; s < 6; ++s) a += wts[s] * ep[s * 512 + k];
    A1[row * 512 + k] = __float2bfloat16(a);
    Z[row * 1024 + 512 + k] = __float2bfloat16(h8[i]);
  }
}

// ---------------- tile staging: 128x32 bf16 via global_load_lds ----------------
__device__ __forceinline__ void stage16(const __hip_bfloat16* __restrict__ g, int ld,
                                        int row0, int k0, __hip_bfloat16* lds, int tid)
{
  int c0 = tid, c1 = tid + 256;                    // 16B chunks; row = c>>2, col = (c&3)*8
  const __hip_bfloat16* g0 = g + (long)(row0 + (c0 >> 2)) * ld + k0 + (c0 & 3) * 8;
  const __hip_bfloat16* g1 = g + (long)(row0 + (c1 >> 2)) * ld + k0 + (c1 & 3) * 8;
  char* l0 = (char*)lds + (tid & ~63) * 16;        // wave-uniform base + lane*16 (HW)
  ASYNC16(g0, l0);
  ASYNC16(g1, l0 + 4096);
}

// ---------------- comb GEMM: x = relu(A1 @ Wc^T + b + input*w0) ----------------
__global__ __launch_bounds__(256) void comb_gemm(
    const __hip_bfloat16* __restrict__ A, const __hip_bfloat16* __restrict__ Bt,
    const float* __restrict__ b_comb, const float* __restrict__ W_comb,
    const float* __restrict__ inputv, __hip_bfloat16* __restrict__ Z)
{
  __shared__ __align__(16) __hip_bfloat16 As[128 * 32];
  __shared__ __align__(16) __hip_bfloat16 Bs[128 * 32];
  const int tid = threadIdx.x;
  const int lane = tid & 63, w = tid >> 6;
  const int quad = lane >> 4, l15 = lane & 15;
  const int m0 = blockIdx.y * 128, n0 = blockIdx.x * 128;
  const int wm = (w & 1) * 64, wn = (w >> 1) * 64;

  f32x4 acc[4][4] = {};
  for (int kt = 0; kt < 16; ++kt) {
    int k0 = kt * 32;
    stage16(A, 512, m0, k0, As, tid);
    stage16(Bt, 512, n0, k0, Bs, tid);
    __syncthreads();
    frag8 af[4], bf[4];
#pragma unroll
    for (int i = 0; i < 4; ++i)
      af[i] = *(const frag8*)((const short*)As + (wm + i * 16 + l15) * 32 + quad * 8);
#pragma unroll
    for (int j = 0; j < 4; ++j)
      bf[j] = *(const frag8*)((const short*)Bs + (wn + j * 16 + l15) * 32 + quad * 8);
#pragma unroll
    for (int i = 0; i < 4; ++i)
#pragma unroll
      for (int j = 0; j < 4; ++j)
        acc[i][j] = __builtin_amdgcn_mfma_f32_16x16x32_bf16(af[i], bf[j], acc[i][j], 0, 0, 0);
    __syncthreads();
  }
  float bc[4], w0[4];
#pragma unroll
  for (int j = 0; j < 4; ++j) {
    int col = n0 + wn + j * 16 + l15;
    bc[j] = b_comb[col];
    w0[j] = W_comb[col * 513];      // column 0 of W_comb multiplies input
  }
#pragma unroll
  for (int i = 0; i < 4; ++i) {
#pragma unroll
    for (int r = 0; r < 4; ++r) {
      int row = m0 + wm + i * 16 + quad * 4 + r;
      float iv = inputv[row];
#pragma unroll
      for (int j = 0; j < 4; ++j) {
        int col = n0 + wn + j * 16 + l15;
        float v = acc[i][j][r] + bc[j] + iv * w0[j];
        Z[(long)row * 1024 + col] = __float2bfloat16(fmaxf(v, 0.0f));
      }
    }
  }
}

// ---------------- gates GEMM + LSTM epilogue ----------------
__global__ __launch_bounds__(256) void gates_gemm(
    const __hip_bfloat16* __restrict__ Zm, const __hip_bfloat16* __restrict__ Wg,
    const float* __restrict__ biasg, const float* __restrict__ cell,
    float* __restrict__ outH, float* __restrict__ outC)
{
  __shared__ __align__(16) float smemf[64 * 132];          // 33792 B, aliased
  __hip_bfloat16* As = (__hip_bfloat16*)smemf;             // 8 KB
  __hip_bfloat16* Bs = (__hip_bfloat16*)smemf + 4096;      // 8 KB
  float* Cl = smemf;                                       // 64x132 fp32
  const int tid = threadIdx.x;
  const int lane = tid & 63, w = tid >> 6;
  const int quad = lane >> 4, l15 = lane & 15;
  const int m0 = blockIdx.y * 128, n0 = blockIdx.x * 128;
  const int wm = (w & 1) * 64, wn = (w >> 1) * 64;

  f32x4 acc[4][4] = {};
  for (int kt = 0; kt < 32; ++kt) {
    int k0 = kt * 32;
    stage16(Zm, 1024, m0, k0, As, tid);
    stage16(Wg, 1024, n0, k0, Bs, tid);
    __syncthreads();
    frag8 af[4], bf[4];
#pragma unroll
    for (int i = 0; i < 4; ++i)
      af[i] = *(const frag8*)((const short*)As + (wm + i * 16 + l15) * 32 + quad * 8);
#pragma unroll
    for (int j = 0; j < 4; ++j)
      bf[j] = *(const frag8*)((const short*)Bs + (wn + j * 16 + l15) * 32 + quad * 8);
#pragma unroll
    for (int i = 0; i < 4; ++i)
#pragma unroll
      for (int j = 0; j < 4; ++j)
        acc[i][j] = __builtin_amdgcn_mfma_f32_16x16x32_bf16(af[i], bf[j], acc[i][j], 0, 0, 0);
    __syncthreads();
  }
  // epilogue in two 64-row halves through padded LDS (stride 132 -> conflict-free)
  for (int hh = 0; hh < 2; ++hh) {
    if ((w & 1) == hh) {
#pragma unroll
      for (int i = 0; i < 4; ++i)
#pragma unroll
        for (int j = 0; j < 4; ++j)
#pragma unroll
          for (int r = 0; r < 4; ++r)
            Cl[(i * 16 + quad * 4 + r) * 132 + wn + j * 16 + l15] = acc[i][j][r];
    }
    __syncthreads();
#pragma unroll
    for (int it = 0; it < 8; ++it) {
      int p = tid + it * 256;
      int rl = p >> 5, ul = p & 31;
      long row = m0 + hh * 64 + rl;
      int u = (n0 >> 2) + ul;
      float4 gv = *(const float4*)(Cl + rl * 132 + ul * 4);
      float4 bv = *(const float4*)(biasg + n0 + ul * 4);
      float ig = gv.x + bv.x, fg = gv.y + bv.y, gg = gv.z + bv.z, og = gv.w + bv.w;
      float cv = cell[row * 512 + u];
      float cn = sigmoid_(fg) * cv + sigmoid_(ig) * tanh_(gg);
      float hn = sigmoid_(og) * tanh_(cn);
      outH[row * 512 + u] = hn;
      outC[row * 512 + u] = cn;
    }
    __syncthreads();
  }
}

// ---------------- output GEMV: one wave per row ----------------
__global__ __launch_bounds__(256) void out_gemv(
    const float* __restrict__ h, const float* __restrict__ W_out,
    const float* __restrict__ b_out, float* __restrict__ out)
{
  __shared__ float wl[512];
  const int tid = threadIdx.x;
  for (int i = tid; i < 512; i += 256) wl[i] = W_out[i];
  __syncthreads();
  const int w = tid >> 6, lane = tid & 63;
  const long row = (long)blockIdx.x * 4 + w;
  float s = 0.f;
#pragma unroll
  for (int i = 0; i < 8; ++i) {
    int k = lane + i * 64;
    s += h[row * 512 + k] * wl[k];
  }
#pragma unroll
  for (int d = 32; d > 0; d >>= 1) s += __shfl_xor(s, d);
  if (lane == 0) out[row] = s + b_out[0];
}

extern "C" void kernel_launch(void* const* d_in, const int* in_sizes, int n_in,
                              void* d_out, int out_size, void* d_ws, size_t ws_size,
                              hipStream_t stream) {
  const float* inputv = (const float*)d_in[0];
  const float* hidden = (const float*)d_in[1];
  const float* cell   = (const float*)d_in[2];
  const float* enc    = (const float*)d_in[3];
  const float* W_attn = (const float*)d_in[4];
  const float* b_attn = (const float*)d_in[5];
  const float* W_comb = (const float*)d_in[6];
  const float* b_comb = (const float*)d_in[7];
  const float* W_ih   = (const float*)d_in[8];
  const float* W_hh   = (const float*)d_in[9];
  const float* b_ih   = (const float*)d_in[10];
  const float* b_hh   = (const float*)d_in[11];
  const float* W_out  = (const float*)d_in[12];
  const float* b_out  = (const float*)d_in[13];

  float* out  = (float*)d_out;
  float* outO = out;                       // [16384]
  float* outH = out + 16384;               // [16384,512]
  float* outC = out + 8404992;             // [16384,512]
  float* outA = out + 16793600;            // [16384,1,6]

  char* ws = (char*)d_ws;
  __hip_bfloat16* Z   = (__hip_bfloat16*)ws;                 // [16384,1024] x|hidden bf16
  __hip_bfloat16* A1  = (__hip_bfloat16*)(ws + 33554432);    // [16384,512] attn_applied bf16
  __hip_bfloat16* Wc  = (__hip_bfloat16*)(ws + 50331648);    // [512,512]
  __hip_bfloat16* Wg  = (__hip_bfloat16*)(ws + 50855936);    // [2048,1024]
  float*          bg  = (float*)(ws + 55050240);             // [2048]

  prep_kernel<<<9224, 256, 0, stream>>>(W_comb, W_ih, W_hh, b_ih, b_hh, Wc, Wg, bg);
  attn_kernel<<<4096, 256, 0, stream>>>(inputv, hidden, cell, enc, W_attn, b_attn, A1, Z, outA);
  comb_gemm<<<dim3(4, 128), 256, 0, stream>>>(A1, Wc, b_comb, W_comb, inputv, Z);
  gates_gemm<<<dim3(16, 128), 256, 0, stream>>>(Z, Wg, bg, cell, outH, outC);
  out_gemv<<<4096, 256, 0, stream>>>(outH, W_out, b_out, outO);
}

// Round 2
// 503.920 us; speedup vs baseline: 1.0572x; 1.0572x over previous
//
#include <hip/hip_runtime.h>
#include <hip/hip_bf16.h>

typedef __attribute__((ext_vector_type(8))) short frag8;
typedef __attribute__((ext_vector_type(4))) float f32x4;

#define ASYNC16(gsrc, ldst) \
  __builtin_amdgcn_global_load_lds((const __attribute__((address_space(1))) void*)(gsrc), \
                                   (__attribute__((address_space(3))) void*)(ldst), 16, 0, 0)

__device__ __forceinline__ float sigmoid_(float x) { return 1.0f / (1.0f + __expf(-x)); }
__device__ __forceinline__ float tanh_(float x)    { return 1.0f - 2.0f / (__expf(2.0f * x) + 1.0f); }

// ---------------- prep: weight conversion / reorder ----------------
// Wg[n'][k]: n' = (u>>4)*64 + j*16 + (u&15)  (u=unit, j=gate i/f/g/o)
// k<512 -> W_ih[:, k], k>=512 -> W_hh[:, k-512]; torch row n = j*512 + u
__global__ __launch_bounds__(256) void prep_kernel(
    const float* __restrict__ W_comb, const float* __restrict__ W_ih,
    const float* __restrict__ W_hh, const float* __restrict__ b_ih,
    const float* __restrict__ b_hh,
    __hip_bfloat16* __restrict__ Wc, __hip_bfloat16* __restrict__ Wg,
    float* __restrict__ biasg)
{
  int idx = blockIdx.x * 256 + threadIdx.x;
  const int NW = 2048 * 1024, NC = 512 * 512;
  if (idx < NW) {
    int np = idx >> 10, k = idx & 1023;
    int j = (np >> 4) & 3;
    int u = ((np >> 6) << 4) | (np & 15);
    int n = j * 512 + u;
    float v = (k < 512) ? W_ih[n * 512 + k] : W_hh[n * 512 + (k - 512)];
    Wg[idx] = __float2bfloat16(v);
  } else if (idx < NW + NC) {
    int t = idx - NW;
    int n = t >> 9, k = t & 511;
    Wc[t] = __float2bfloat16(W_comb[n * 513 + 1 + k]);   // skip col 0 (input)
  } else if (idx < NW + NC + 2048) {
    int np = idx - NW - NC;
    int j = (np >> 4) & 3;
    int u = ((np >> 6) << 4) | (np & 15);
    int n = j * 512 + u;
    biasg[np] = b_ih[n] + b_hh[n];
  }
}

// ---------------- attention: one wave per row, 8 contiguous k per lane ----------------
__global__ __launch_bounds__(256) void attn_kernel(
    const float* __restrict__ inputv, const float* __restrict__ hidden,
    const float* __restrict__ cell, const float* __restrict__ enc,
    const float* __restrict__ W_attn, const float* __restrict__ b_attn,
    __hip_bfloat16* __restrict__ A1, __hip_bfloat16* __restrict__ Z,
    float* __restrict__ outA)
{
  __shared__ float Wlh[6 * 1024];   // [s][0..511]=hidden w, [s][512..1023]=cell w
  __shared__ float Wl0[6];
  const int tid = threadIdx.x;
  for (int i = tid; i < 6 * 1024; i += 256) {
    int s = i >> 10, k = i & 1023;
    Wlh[i] = W_attn[s * 1025 + 1 + k];
  }
  if (tid < 6) Wl0[tid] = W_attn[tid * 1025];
  __syncthreads();
  const int w = tid >> 6, lane = tid & 63;
  const long row = (long)blockIdx.x * 4 + w;
  const int k8 = lane * 8;

  const float4* hp4 = (const float4*)(hidden + row * 512 + k8);
  const float4* cp4 = (const float4*)(cell + row * 512 + k8);
  float4 h0 = hp4[0], h1 = hp4[1];
  float4 c0 = cp4[0], c1 = cp4[1];

  float acc[6];
#pragma unroll
  for (int s = 0; s < 6; ++s) {
    const float4* wh = (const float4*)(Wlh + s * 1024 + k8);
    const float4* wc = (const float4*)(Wlh + s * 1024 + 512 + k8);
    float4 a0 = wh[0], a1 = wh[1], b0 = wc[0], b1 = wc[1];
    acc[s] = h0.x * a0.x + h0.y * a0.y + h0.z * a0.z + h0.w * a0.w
           + h1.x * a1.x + h1.y * a1.y + h1.z * a1.z + h1.w * a1.w
           + c0.x * b0.x + c0.y * b0.y + c0.z * b0.z + c0.w * b0.w
           + c1.x * b1.x + c1.y * b1.y + c1.z * b1.z + c1.w * b1.w;
  }
  float iv = inputv[row];
  float logit[6];
#pragma unroll
  for (int s = 0; s < 6; ++s) {
    float a = acc[s];
#pragma unroll
    for (int d = 32; d > 0; d >>= 1) a += __shfl_xor(a, d);
    logit[s] = a + iv * Wl0[s] + b_attn[s];
  }
  float mx = logit[0];
#pragma unroll
  for (int s = 1; s < 6; ++s) mx = fmaxf(mx, logit[s]);
  float wts[6], tot = 0.f;
#pragma unroll
  for (int s = 0; s < 6; ++s) { wts[s] = __expf(logit[s] - mx); tot += wts[s]; }
  float rt = 1.f / tot;
#pragma unroll
  for (int s = 0; s < 6; ++s) wts[s] *= rt;
  if (lane < 6) {
    float mw = 0.f;
#pragma unroll
    for (int s = 0; s < 6; ++s) if (lane == s) mw = wts[s];
    outA[row * 6 + lane] = mw;
  }
  // attn_applied = sum_s wts[s] * enc[row, s, :]
  float a8[8] = {0.f, 0.f, 0.f, 0.f, 0.f, 0.f, 0.f, 0.f};
  const float* ep = enc + row * 3072 + k8;
#pragma unroll
  for (int s = 0; s < 6; ++s) {
    float4 e0 = *(const float4*)(ep + s * 512);
    float4 e1 = *(const float4*)(ep + s * 512 + 4);
    float ws_ = wts[s];
    a8[0] += ws_ * e0.x; a8[1] += ws_ * e0.y; a8[2] += ws_ * e0.z; a8[3] += ws_ * e0.w;
    a8[4] += ws_ * e1.x; a8[5] += ws_ * e1.y; a8[6] += ws_ * e1.z; a8[7] += ws_ * e1.w;
  }
  union { frag8 v; __hip_bfloat16 h[8]; } pa, ph;
  float hv8[8] = {h0.x, h0.y, h0.z, h0.w, h1.x, h1.y, h1.z, h1.w};
#pragma unroll
  for (int i = 0; i < 8; ++i) { pa.h[i] = __float2bfloat16(a8[i]); ph.h[i] = __float2bfloat16(hv8[i]); }
  *(frag8*)(A1 + row * 512 + k8) = pa.v;
  *(frag8*)(Z + row * 1024 + 512 + k8) = ph.v;
}

// ---------------- tile staging: 128x32 bf16 via global_load_lds ----------------
__device__ __forceinline__ void stage16(const __hip_bfloat16* __restrict__ g, int ld,
                                        int row0, int k0, __hip_bfloat16* lds, int tid)
{
  int c0 = tid, c1 = tid + 256;                    // 16B chunks; row = c>>2, col = (c&3)*8
  const __hip_bfloat16* g0 = g + (long)(row0 + (c0 >> 2)) * ld + k0 + (c0 & 3) * 8;
  const __hip_bfloat16* g1 = g + (long)(row0 + (c1 >> 2)) * ld + k0 + (c1 & 3) * 8;
  char* l0 = (char*)lds + (tid & ~63) * 16;        // wave-uniform base + lane*16 (HW)
  ASYNC16(g0, l0);
  ASYNC16(g1, l0 + 4096);
}

// ---------------- comb GEMM: x = relu(A1 @ Wc^T + b + input*w0) ----------------
__global__ __launch_bounds__(256) void comb_gemm(
    const __hip_bfloat16* __restrict__ A, const __hip_bfloat16* __restrict__ Bt,
    const float* __restrict__ b_comb, const float* __restrict__ W_comb,
    const float* __restrict__ inputv, __hip_bfloat16* __restrict__ Z)
{
  __shared__ __align__(16) __hip_bfloat16 As[2][128 * 32];
  __shared__ __align__(16) __hip_bfloat16 Bs[2][128 * 32];
  const int tid = threadIdx.x;
  const int lane = tid & 63, w = tid >> 6;
  const int quad = lane >> 4, l15 = lane & 15;
  const int m0 = blockIdx.y * 128, n0 = blockIdx.x * 128;
  const int wm = (w & 1) * 64, wn = (w >> 1) * 64;

  f32x4 acc[4][4] = {};
  for (int kt = 0; kt < 8; ++kt) {
    int k0 = kt * 64;
    stage16(A, 512, m0, k0, As[0], tid);
    stage16(A, 512, m0, k0 + 32, As[1], tid);
    stage16(Bt, 512, n0, k0, Bs[0], tid);
    stage16(Bt, 512, n0, k0 + 32, Bs[1], tid);
    __syncthreads();
#pragma unroll
    for (int h = 0; h < 2; ++h) {
      frag8 af[4], bf[4];
#pragma unroll
      for (int i = 0; i < 4; ++i)
        af[i] = *(const frag8*)((const short*)As[h] + (wm + i * 16 + l15) * 32 + quad * 8);
#pragma unroll
      for (int j = 0; j < 4; ++j)
        bf[j] = *(const frag8*)((const short*)Bs[h] + (wn + j * 16 + l15) * 32 + quad * 8);
#pragma unroll
      for (int i = 0; i < 4; ++i)
#pragma unroll
        for (int j = 0; j < 4; ++j)
          acc[i][j] = __builtin_amdgcn_mfma_f32_16x16x32_bf16(af[i], bf[j], acc[i][j], 0, 0, 0);
    }
    __syncthreads();
  }
  float bc[4], w0[4];
#pragma unroll
  for (int j = 0; j < 4; ++j) {
    int col = n0 + wn + j * 16 + l15;
    bc[j] = b_comb[col];
    w0[j] = W_comb[col * 513];      // column 0 of W_comb multiplies input
  }
#pragma unroll
  for (int i = 0; i < 4; ++i) {
#pragma unroll
    for (int r = 0; r < 4; ++r) {
      int row = m0 + wm + i * 16 + quad * 4 + r;
      float iv = inputv[row];
#pragma unroll
      for (int j = 0; j < 4; ++j) {
        int col = n0 + wn + j * 16 + l15;
        float v = acc[i][j][r] + bc[j] + iv * w0[j];
        Z[(long)row * 1024 + col] = __float2bfloat16(fmaxf(v, 0.0f));
      }
    }
  }
}

// ---------------- gates GEMM + register LSTM epilogue ----------------
// Wg column layout: n' = (u>>4)*64 + j*16 + (u&15) -> lane l15's four j-frags
// are the 4 gates of unit u = (n0+wn)/4 + l15.
__global__ __launch_bounds__(256) void gates_gemm(
    const __hip_bfloat16* __restrict__ Zm, const __hip_bfloat16* __restrict__ Wg,
    const float* __restrict__ biasg, const float* __restrict__ cell,
    float* __restrict__ outH, float* __restrict__ outC)
{
  __shared__ __align__(16) __hip_bfloat16 As[2][128 * 32];
  __shared__ __align__(16) __hip_bfloat16 Bs[2][128 * 32];
  const int tid = threadIdx.x;
  const int lane = tid & 63, w = tid >> 6;
  const int quad = lane >> 4, l15 = lane & 15;
  const int m0 = blockIdx.y * 128, n0 = blockIdx.x * 128;
  const int wm = (w & 1) * 64, wn = (w >> 1) * 64;

  f32x4 acc[4][4] = {};
  for (int kt = 0; kt < 16; ++kt) {
    int k0 = kt * 64;
    stage16(Zm, 1024, m0, k0, As[0], tid);
    stage16(Zm, 1024, m0, k0 + 32, As[1], tid);
    stage16(Wg, 1024, n0, k0, Bs[0], tid);
    stage16(Wg, 1024, n0, k0 + 32, Bs[1], tid);
    __syncthreads();
#pragma unroll
    for (int h = 0; h < 2; ++h) {
      frag8 af[4], bf[4];
#pragma unroll
      for (int i = 0; i < 4; ++i)
        af[i] = *(const frag8*)((const short*)As[h] + (wm + i * 16 + l15) * 32 + quad * 8);
#pragma unroll
      for (int j = 0; j < 4; ++j)
        bf[j] = *(const frag8*)((const short*)Bs[h] + (wn + j * 16 + l15) * 32 + quad * 8);
#pragma unroll
      for (int i = 0; i < 4; ++i)
#pragma unroll
        for (int j = 0; j < 4; ++j)
          acc[i][j] = __builtin_amdgcn_mfma_f32_16x16x32_bf16(af[i], bf[j], acc[i][j], 0, 0, 0);
    }
    __syncthreads();
  }
  // register epilogue: lane handles unit u for 16 rows
  const int u = ((n0 + wn) >> 2) + l15;
  const float bi = biasg[n0 + wn + l15];
  const float bfg = biasg[n0 + wn + 16 + l15];
  const float bgg = biasg[n0 + wn + 32 + l15];
  const float bo = biasg[n0 + wn + 48 + l15];
#pragma unroll
  for (int i = 0; i < 4; ++i) {
#pragma unroll
    for (int r = 0; r < 4; ++r) {
      long row = m0 + wm + i * 16 + quad * 4 + r;
      float cv = cell[row * 512 + u];
      float ig = acc[i][0][r] + bi;
      float fg = acc[i][1][r] + bfg;
      float gg = acc[i][2][r] + bgg;
      float og = acc[i][3][r] + bo;
      float cn = sigmoid_(fg) * cv + sigmoid_(ig) * tanh_(gg);
      float hn = sigmoid_(og) * tanh_(cn);
      outH[row * 512 + u] = hn;
      outC[row * 512 + u] = cn;
    }
  }
}

// ---------------- output GEMV: one wave per row ----------------
__global__ __launch_bounds__(256) void out_gemv(
    const float* __restrict__ h, const float* __restrict__ W_out,
    const float* __restrict__ b_out, float* __restrict__ out)
{
  __shared__ float wl[512];
  const int tid = threadIdx.x;
  for (int i = tid; i < 512; i += 256) wl[i] = W_out[i];
  __syncthreads();
  const int w = tid >> 6, lane = tid & 63;
  const long row = (long)blockIdx.x * 4 + w;
  const int k8 = lane * 8;
  const float4* hp4 = (const float4*)(h + row * 512 + k8);
  const float4* wp4 = (const float4*)(wl + k8);
  float4 h0 = hp4[0], h1 = hp4[1];
  float4 w0 = wp4[0], w1 = wp4[1];
  float s = h0.x * w0.x + h0.y * w0.y + h0.z * w0.z + h0.w * w0.w
          + h1.x * w1.x + h1.y * w1.y + h1.z * w1.z + h1.w * w1.w;
#pragma unroll
  for (int d = 32; d > 0; d >>= 1) s += __shfl_xor(s, d);
  if (lane == 0) out[row] = s + b_out[0];
}

extern "C" void kernel_launch(void* const* d_in, const int* in_sizes, int n_in,
                              void* d_out, int out_size, void* d_ws, size_t ws_size,
                              hipStream_t stream) {
  const float* inputv = (const float*)d_in[0];
  const float* hidden = (const float*)d_in[1];
  const float* cell   = (const float*)d_in[2];
  const float* enc    = (const float*)d_in[3];
  const float* W_attn = (const float*)d_in[4];
  const float* b_attn = (const float*)d_in[5];
  const float* W_comb = (const float*)d_in[6];
  const float* b_comb = (const float*)d_in[7];
  const float* W_ih   = (const float*)d_in[8];
  const float* W_hh   = (const float*)d_in[9];
  const float* b_ih   = (const float*)d_in[10];
  const float* b_hh   = (const float*)d_in[11];
  const float* W_out  = (const float*)d_in[12];
  const float* b_out  = (const float*)d_in[13];

  float* out  = (float*)d_out;
  float* outO = out;                       // [16384]
  float* outH = out + 16384;               // [16384,512]
  float* outC = out + 8404992;             // [16384,512]
  float* outA = out + 16793600;            // [16384,1,6]

  char* ws = (char*)d_ws;
  __hip_bfloat16* Z   = (__hip_bfloat16*)ws;                 // [16384,1024] x|hidden bf16
  __hip_bfloat16* A1  = (__hip_bfloat16*)(ws + 33554432);    // [16384,512] attn_applied bf16
  __hip_bfloat16* Wc  = (__hip_bfloat16*)(ws + 50331648);    // [512,512]
  __hip_bfloat16* Wg  = (__hip_bfloat16*)(ws + 50855936);    // [2048,1024]
  float*          bg  = (float*)(ws + 55050240);             // [2048]

  prep_kernel<<<9224, 256, 0, stream>>>(W_comb, W_ih, W_hh, b_ih, b_hh, Wc, Wg, bg);
  attn_kernel<<<4096, 256, 0, stream>>>(inputv, hidden, cell, enc, W_attn, b_attn, A1, Z, outA);
  comb_gemm<<<dim3(4, 128), 256, 0, stream>>>(A1, Wc, b_comb, W_comb, inputv, Z);
  gates_gemm<<<dim3(16, 128), 256, 0, stream>>>(Z, Wg, bg, cell, outH, outC);
  out_gemv<<<4096, 256, 0, stream>>>(outH, W_out, b_out, outO);
}